// Round 19
// baseline (171.401 us; speedup 1.0000x reference)
//
#include <hip/hip_runtime.h>
#include <hip/hip_bf16.h>
#include <stdint.h>

#define B_   2
#define N_   2048
#define DIN  2048
#define DOUT 2048
#define H_   32
#define G_   8
#define HD_  64
#define M_   (B_*N_)   // 4096

using short8 = __attribute__((ext_vector_type(8))) short;
using f32x4  = __attribute__((ext_vector_type(4))) float;
using f32x16 = __attribute__((ext_vector_type(16))) float;
using int4v  = __attribute__((ext_vector_type(4))) int;

__device__ __forceinline__ unsigned short f2bf(float f) {
  unsigned int u = __float_as_uint(f);
  unsigned int r = u + 0x7FFFu + ((u >> 16) & 1u);
  return (unsigned short)(r >> 16);
}
__device__ __forceinline__ float bf2f(unsigned short h) {
  return __uint_as_float(((unsigned int)h) << 16);
}

// RoPE column permutation (involution): pairs (e,e+32) land 16 apart in aligned
// 32-col groups. p: [0,16)->id, [16,32)->+16, [32,48)->-16, [48,64)->id.
__device__ __forceinline__ int p63(int e) {
  return (((e >> 4) ^ (e >> 5)) & 1) ? (e ^ 48) : e;
}

// ---------------- merged x-cvt + weight transposes (one dispatch) ----------------
__global__ void k_prep(const float* __restrict__ x, unsigned short* __restrict__ xb,
                       const float* __restrict__ Wq, const float* __restrict__ Wk,
                       const float* __restrict__ Wv, const float* __restrict__ Wo,
                       unsigned short* __restrict__ Wqkv_t, unsigned short* __restrict__ Wo_t) {
  __shared__ float tile[32][33];
  const int ct = blockIdx.x;
  const int tx = threadIdx.x, ty = threadIdx.y;  // (32,8)
  if (ct >= 160) {
    const int i = ((ct - 160) * 64 + blockIdx.y) * 256 + ty * 32 + tx;
    float4 v = reinterpret_cast<const float4*>(x)[i];
    uint2 o;
    o.x = (unsigned int)f2bf(v.x) | ((unsigned int)f2bf(v.y) << 16);
    o.y = (unsigned int)f2bf(v.z) | ((unsigned int)f2bf(v.w) << 16);
    reinterpret_cast<uint2*>(xb)[i] = o;
    return;
  }
  const int r0 = blockIdx.y * 32;
  const float* W;
  unsigned short* dst;
  int C, c0, base, rope;
  if (ct < 64)      { W = Wq; dst = Wqkv_t; C = 2048; c0 = ct*32;      base = 0;    rope = 1; }
  else if (ct < 80) { W = Wk; dst = Wqkv_t; C = 512;  c0 = (ct-64)*32; base = 2048; rope = 1; }
  else if (ct < 96) { W = Wv; dst = Wqkv_t; C = 512;  c0 = (ct-80)*32; base = 2560; rope = 0; }
  else              { W = Wo; dst = Wo_t;   C = 2048; c0 = (ct-96)*32; base = 0;    rope = 0; }
  #pragma unroll
  for (int j = 0; j < 4; ++j)
    tile[ty + j*8][tx] = W[(size_t)(r0 + ty + j*8) * C + c0 + tx];
  __syncthreads();
  #pragma unroll
  for (int j = 0; j < 4; ++j) {
    int colW = c0 + ty + j*8;
    int row  = rope ? ((colW & ~63) | p63(colW & 63)) : colW;
    dst[(size_t)(base + row) * 2048 + r0 + tx] = f2bf(tile[tx][ty + j*8]);
  }
}

// ---------------- fused QKV GEMM, 256x192 8-phase (r18-proven) ----------------
#define QA0 0
#define QB0 32768
#define QA1 57344
#define QB1 90112

#define QP3(ABUF, M, STAGES, WAITS)                                              \
  {                                                                              \
    short8 a0 = rdA(ABUF, M, 0), a1 = rdA(ABUF, M, 1);                           \
    STAGES;                                                                      \
    WAITS;                                                                       \
    __builtin_amdgcn_s_barrier();                                                \
    asm volatile("s_waitcnt lgkmcnt(0)" ::: "memory");                           \
    __builtin_amdgcn_sched_barrier(0);                                           \
    __builtin_amdgcn_s_setprio(1);                                               \
    _Pragma("unroll")                                                            \
    for (int n = 0; n < 6; ++n) {                                                \
      acc[M][n] = __builtin_amdgcn_mfma_f32_16x16x32_bf16(a0, bv[n][0], acc[M][n], 0,0,0); \
      acc[M][n] = __builtin_amdgcn_mfma_f32_16x16x32_bf16(a1, bv[n][1], acc[M][n], 0,0,0); \
    }                                                                            \
    __builtin_amdgcn_s_setprio(0);                                               \
    __builtin_amdgcn_s_barrier();                                                \
  }

__global__ void __launch_bounds__(512, 2)
k_gemm_qkv(const unsigned short* __restrict__ A, const unsigned short* __restrict__ Bt,
           unsigned short* __restrict__ Qp, unsigned short* __restrict__ Kp,
           unsigned short* __restrict__ Vp,
           const float* __restrict__ cosT, const float* __restrict__ sinT) {
  __shared__ unsigned short sm[57344];     // 112 KiB: A0(32K)|B0(24K)|A1(32K)|B1(24K)
  const int tid = threadIdx.x;
  const int wid = tid >> 6, l = tid & 63;
  const int lrow = l & 15, lk = l >> 4;
  const int wm = wid >> 1, wn = wid & 1;   // wave grid 4 x 2

  const int gx   = gridDim.x;              // 16
  const int nwg  = gx * gridDim.y;         // 256
  const int orig = blockIdx.y * gx + blockIdx.x;
  const int q8   = nwg >> 3;
  const int xcd  = orig & 7, lin = orig >> 3;
  const int wg   = xcd * q8 + lin;
  const int bx   = wg % gx, by = wg / gx;
  const int rowA0 = by * 256, rowB0 = bx * 192;

  f32x4 acc[4][6];
  #pragma unroll
  for (int m = 0; m < 4; ++m)
    #pragma unroll
    for (int n = 0; n < 6; ++n)
      #pragma unroll
      for (int r = 0; r < 4; ++r) acc[m][n][r] = 0.f;

  const int srowoff = wid*8 + (l >> 3);
  const int skoff   = (((l & 7) ^ ((l >> 3) & 7)) << 3);   // inverse 3-bit swizzle
  auto stageU = [&](const unsigned short* Mat, int rowBase, int t, int bufByte, int u) {
    const unsigned short* g = Mat + (size_t)(rowBase + u*64 + srowoff) * 2048 + t*64 + skoff;
    __builtin_amdgcn_global_load_lds(
        (const __attribute__((address_space(1))) unsigned int*)g,
        (__attribute__((address_space(3))) unsigned int*)
            ((char*)sm + bufByte + u*8192 + wid*1024),
        16, 0, 0);
  };

  const int aswz = (lrow & 7) << 4;
  auto rdA = [&](int bufByte, int m, int kk) -> short8 {
    int byte = bufByte + (wm*64 + m*16 + lrow)*128 + ((kk*64 + lk*16) ^ aswz);
    return *reinterpret_cast<const short8*>((char*)sm + byte);
  };
  auto rdB = [&](int bufByte, int n, int kk) -> short8 {
    int byte = bufByte + (wn*96 + n*16 + lrow)*128 + ((kk*64 + lk*16) ^ aswz);
    return *reinterpret_cast<const short8*>((char*)sm + byte);
  };

  short8 bv[6][2];

  stageU(Bt, rowB0, 0, QB0, 0); stageU(Bt, rowB0, 0, QB0, 1); stageU(Bt, rowB0, 0, QB0, 2);
  stageU(A,  rowA0, 0, QA0, 0); stageU(A,  rowA0, 0, QA0, 1);
  stageU(A,  rowA0, 0, QA0, 2); stageU(A,  rowA0, 0, QA0, 3);
  stageU(Bt, rowB0, 1, QB1, 0); stageU(Bt, rowB0, 1, QB1, 1); stageU(Bt, rowB0, 1, QB1, 2);
  asm volatile("s_waitcnt vmcnt(3)" ::: "memory");
  __builtin_amdgcn_sched_barrier(0);
  __builtin_amdgcn_s_barrier();

  for (int i = 0; i < 16; ++i) {
    const int t = 2*i;
    const bool more = (i < 15);

    #pragma unroll
    for (int n = 0; n < 6; ++n) { bv[n][0] = rdB(QB0, n, 0); bv[n][1] = rdB(QB0, n, 1); }
    QP3(QA0, 0, { stageU(A, rowA0, t+1, QA1, 0); stageU(A, rowA0, t+1, QA1, 1); }, {});
    QP3(QA0, 1, { stageU(A, rowA0, t+1, QA1, 2); stageU(A, rowA0, t+1, QA1, 3); }, {});
    QP3(QA0, 2, { if (more) { stageU(Bt, rowB0, t+2, QB0, 0);
                              stageU(Bt, rowB0, t+2, QB0, 1); } }, {});
    QP3(QA0, 3, { if (more) stageU(Bt, rowB0, t+2, QB0, 2); },
                { if (more) { asm volatile("s_waitcnt vmcnt(3)" ::: "memory"); }
                  else      { asm volatile("s_waitcnt vmcnt(0)" ::: "memory"); }
                  __builtin_amdgcn_sched_barrier(0); });

    #pragma unroll
    for (int n = 0; n < 6; ++n) { bv[n][0] = rdB(QB1, n, 0); bv[n][1] = rdB(QB1, n, 1); }
    QP3(QA1, 0, { if (more) { stageU(A, rowA0, t+2, QA0, 0);
                              stageU(A, rowA0, t+2, QA0, 1); } }, {});
    QP3(QA1, 1, { if (more) { stageU(A, rowA0, t+2, QA0, 2);
                              stageU(A, rowA0, t+2, QA0, 3); } }, {});
    QP3(QA1, 2, { if (more) { stageU(Bt, rowB0, t+3, QB1, 0);
                              stageU(Bt, rowB0, t+3, QB1, 1); } }, {});
    QP3(QA1, 3, { if (more) stageU(Bt, rowB0, t+3, QB1, 2); },
                { if (more) { asm volatile("s_waitcnt vmcnt(3)" ::: "memory"); }
                  else      { asm volatile("s_waitcnt vmcnt(0)" ::: "memory"); }
                  __builtin_amdgcn_sched_barrier(0); });
  }

  // ---- epilogue: per 16-col fragment, classify Q/K/V (boundaries 32-aligned) ----
  #pragma unroll
  for (int m = 0; m < 4; ++m) {
    const int row0 = rowA0 + wm*64 + m*16 + lk*4;
    const int b    = row0 >> 11;
    const int key  = row0 & 2047;
    #pragma unroll
    for (int j = 0; j < 3; ++j) {
      const int col0 = rowB0 + wn*96 + j*32 + lrow;
      if (col0 >= 2560) {
        const size_t tbase = (size_t)(key >> 5)*2048 + (size_t)((key >> 4) & 1)*512
                           + (size_t)((key >> 3) & 1)*256 + (size_t)(key & 7);
        #pragma unroll
        for (int f = 0; f < 2; ++f) {
          const int cv = col0 + f*16 - 2560;
          const int gq = cv >> 6, d = cv & 63;
          const size_t addr = (size_t)(b*8 + gq)*131072 + tbase
                            + (size_t)(d >> 5)*1024 + (size_t)(d & 31)*8;
          ushort4 st;
          st.x = f2bf(acc[m][2*j+f][0]); st.y = f2bf(acc[m][2*j+f][1]);
          st.z = f2bf(acc[m][2*j+f][2]); st.w = f2bf(acc[m][2*j+f][3]);
          *reinterpret_cast<ushort4*>(Vp + addr) = st;
        }
      } else {
        const bool isQ = (col0 < 2048);
        const float scale = isQ ? 0.18033688011112042f : 1.0f;
        unsigned short* dst = isQ ? Qp : Kp;
        const int ch = col0 & 63;
        const int e  = ch - ((ch & 32) ? 16 : 0);
        const int hg = isQ ? (col0 >> 6) : ((col0 - 2048) >> 6);
        const size_t chunk = (size_t)(isQ ? (b*32 + hg) : (b*8 + hg)) * 64;
        #pragma unroll
        for (int r = 0; r < 4; ++r) {
          const int pos = key + r;
          const float cc = cosT[pos*64 + e] * scale;
          const float ss = sinT[pos*64 + e] * scale;
          const float x1 = acc[m][2*j][r];
          const float x2 = acc[m][2*j+1][r];
          const size_t off = (chunk + (pos >> 5)) * 2048
                           + (size_t)(e >> 4)*512 + (size_t)((e >> 3) & 1)*256
                           + (size_t)(pos & 31)*8 + (e & 7);
          dst[off]        = f2bf(x1*cc - x2*ss);
          dst[off + 1024] = f2bf(x2*cc + x1*ss);
        }
      }
    }
  }
}

// ---------------- output GEMM: ctx @ Wo^T -> f32, 256x128 8-phase (r17-proven) ----------------
#define OA0 0
#define OB0 32768
#define OA1 49152
#define OB1 81920

#define OPHASE(ABUF, M, STAGES, WAITS)                                           \
  {                                                                              \
    short8 a0 = rdA(ABUF, M, 0), a1 = rdA(ABUF, M, 1);                           \
    STAGES;                                                                      \
    WAITS;                                                                       \
    __builtin_amdgcn_s_barrier();                                                \
    asm volatile("s_waitcnt lgkmcnt(0)" ::: "memory");                           \
    __builtin_amdgcn_sched_barrier(0);                                           \
    __builtin_amdgcn_s_setprio(1);                                               \
    _Pragma("unroll")                                                            \
    for (int n = 0; n < 4; ++n) {                                                \
      acc[M][n] = __builtin_amdgcn_mfma_f32_16x16x32_bf16(a0, bv[n][0], acc[M][n], 0,0,0); \
      acc[M][n] = __builtin_amdgcn_mfma_f32_16x16x32_bf16(a1, bv[n][1], acc[M][n], 0,0,0); \
    }                                                                            \
    __builtin_amdgcn_s_setprio(0);                                               \
    __builtin_amdgcn_s_barrier();                                                \
  }

__global__ void __launch_bounds__(512, 2)
k_gemm_out(const unsigned short* __restrict__ A, const unsigned short* __restrict__ Bt,
           float* __restrict__ C) {
  __shared__ unsigned short sm[49152];     // 96 KiB
  const int tid = threadIdx.x;
  const int wid = tid >> 6, l = tid & 63;
  const int lrow = l & 15, lk = l >> 4;
  const int wm = wid >> 1, wn = wid & 1;   // wave grid 4 x 2

  const int gx   = gridDim.x;              // 16
  const int nwg  = gx * gridDim.y;         // 256
  const int orig = blockIdx.y * gx + blockIdx.x;
  const int q8   = nwg >> 3;
  const int xcd  = orig & 7, lin = orig >> 3;
  const int wg   = xcd * q8 + lin;
  const int bx   = wg % gx, by = wg / gx;
  const int rowA0 = by * 256, rowB0 = bx * 128;

  f32x4 acc[4][4];
  #pragma unroll
  for (int m = 0; m < 4; ++m)
    #pragma unroll
    for (int n = 0; n < 4; ++n)
      #pragma unroll
      for (int r = 0; r < 4; ++r) acc[m][n][r] = 0.f;

  const int srowoff = wid*8 + (l >> 3);
  const int skoff   = (((l & 7) ^ ((l >> 3) & 7)) << 3);
  auto stageU = [&](const unsigned short* Mat, int rowBase, int t, int bufByte, int u) {
    const unsigned short* g = Mat + (size_t)(rowBase + u*64 + srowoff) * 2048 + t*64 + skoff;
    __builtin_amdgcn_global_load_lds(
        (const __attribute__((address_space(1))) unsigned int*)g,
        (__attribute__((address_space(3))) unsigned int*)
            ((char*)sm + bufByte + u*8192 + wid*1024),
        16, 0, 0);
  };

  const int aswz = (lrow & 7) << 4;
  auto rdA = [&](int bufByte, int m, int kk) -> short8 {
    int byte = bufByte + (wm*64 + m*16 + lrow)*128 + ((kk*64 + lk*16) ^ aswz);
    return *reinterpret_cast<const short8*>((char*)sm + byte);
  };
  auto rdB = [&](int bufByte, int n, int kk) -> short8 {
    int byte = bufByte + (wn*64 + n*16 + lrow)*128 + ((kk*64 + lk*16) ^ aswz);
    return *reinterpret_cast<const short8*>((char*)sm + byte);
  };

  short8 bv[4][2];

  stageU(Bt, rowB0, 0, OB0, 0); stageU(Bt, rowB0, 0, OB0, 1);
  stageU(A,  rowA0, 0, OA0, 0); stageU(A,  rowA0, 0, OA0, 1);
  stageU(A,  rowA0, 0, OA0, 2); stageU(A,  rowA0, 0, OA0, 3);
  stageU(Bt, rowB0, 1, OB1, 0); stageU(Bt, rowB0, 1, OB1, 1);
  asm volatile("s_waitcnt vmcnt(2)" ::: "memory");
  __builtin_amdgcn_sched_barrier(0);
  __builtin_amdgcn_s_barrier();

  for (int i = 0; i < 16; ++i) {
    const int t = 2*i;
    const bool more = (i < 15);

    #pragma unroll
    for (int n = 0; n < 4; ++n) { bv[n][0] = rdB(OB0, n, 0); bv[n][1] = rdB(OB0, n, 1); }
    OPHASE(OA0, 0, { stageU(A, rowA0, t+1, OA1, 0); stageU(A, rowA0, t+1, OA1, 1); }, {});
    OPHASE(OA0, 1, { stageU(A, rowA0, t+1, OA1, 2); stageU(A, rowA0, t+1, OA1, 3); }, {});
    OPHASE(OA0, 2, { if (more) { stageU(Bt, rowB0, t+2, OB0, 0);
                                 stageU(Bt, rowB0, t+2, OB0, 1); } }, {});
    OPHASE(OA0, 3, {}, { if (more) { asm volatile("s_waitcnt vmcnt(2)" ::: "memory"); }
                         else      { asm volatile("s_waitcnt vmcnt(0)" ::: "memory"); }
                         __builtin_amdgcn_sched_barrier(0); });

    #pragma unroll
    for (int n = 0; n < 4; ++n) { bv[n][0] = rdB(OB1, n, 0); bv[n][1] = rdB(OB1, n, 1); }
    OPHASE(OA1, 0, { if (more) { stageU(A, rowA0, t+2, OA0, 0);
                                 stageU(A, rowA0, t+2, OA0, 1); } }, {});
    OPHASE(OA1, 1, { if (more) { stageU(A, rowA0, t+2, OA0, 2);
                                 stageU(A, rowA0, t+2, OA0, 3); } }, {});
    OPHASE(OA1, 2, { if (more) { stageU(Bt, rowB0, t+3, OB1, 0);
                                 stageU(Bt, rowB0, t+3, OB1, 1); } }, {});
    OPHASE(OA1, 3, {}, { if (more) { asm volatile("s_waitcnt vmcnt(2)" ::: "memory"); }
                         else      { asm volatile("s_waitcnt vmcnt(0)" ::: "memory"); }
                         __builtin_amdgcn_sched_barrier(0); });
  }

  #pragma unroll
  for (int m = 0; m < 4; ++m) {
    int row0 = rowA0 + wm*64 + m*16 + lk*4;
    #pragma unroll
    for (int n = 0; n < 4; ++n) {
      int col = rowB0 + wn*64 + n*16 + lrow;
      #pragma unroll
      for (int r = 0; r < 4; ++r)
        C[(size_t)(row0 + r) * DOUT + col] = acc[m][n][r];
    }
  }
}

// ---------------- causal GQA flash attention v19: uniform 65-body blocks ----------------
// Block (c, pr) processes qt=pr then qt=63-pr sequentially (same 4 heads, shared
// LDS staging, block-uniform loop counts) -> every block is exactly 65 bodies,
// zero drain. 512 blocks = 2/CU steady. Fixed-max softmax (r16); l-shuffle
// deferred to the epilogue (sum is linear without rescaling).
__global__ void __launch_bounds__(256, 3)
k_attn(const unsigned short* __restrict__ Qp, const unsigned short* __restrict__ Kp,
       const unsigned short* __restrict__ Vp, unsigned short* __restrict__ ctx) {
  __shared__ unsigned short kvlds[2][4096];   // [buf][ K:0..2047 | V:2048..4095 ]
  const int bid = blockIdx.x;            // 0..511
  const int c   = bid & 15;              // (b,g) chunk -> fixed XCD
  const int b   = c >> 3, g = c & 7;
  const int pr  = bid >> 4;              // 0..31
  const int tid = threadIdx.x;
  const int hh  = tid >> 6;              // wave id = head within group
  const int h   = g*4 + hh;
  const int l   = tid & 63;
  const int lq  = l & 31, hi = l >> 5;

  const unsigned short* ksrc = Kp + (size_t)c*131072 + hh*512 + l*8;
  const unsigned short* vsrc = Vp + (size_t)c*131072 + hh*512 + l*8;

  auto stage = [&](int t, int buf) {
    __builtin_amdgcn_global_load_lds(
        (const __attribute__((address_space(1))) unsigned int*)(ksrc + (size_t)t*2048),
        (__attribute__((address_space(3))) unsigned int*)((char*)&kvlds[buf][0] + hh*1024),
        16, 0, 0);
    __builtin_amdgcn_global_load_lds(
        (const __attribute__((address_space(1))) unsigned int*)(vsrc + (size_t)t*2048),
        (__attribute__((address_space(3))) unsigned int*)((char*)&kvlds[buf][2048] + hh*1024),
        16, 0, 0);
  };

  auto process = [&](int qt) {
    const unsigned short* qbase = Qp + ((size_t)(b*32 + h)*64 + qt)*2048 + l*8;
    short8 qf0 = *reinterpret_cast<const short8*>(qbase);
    short8 qf1 = *reinterpret_cast<const short8*>(qbase + 512);
    short8 qf2 = *reinterpret_cast<const short8*>(qbase + 1024);
    short8 qf3 = *reinterpret_cast<const short8*>(qbase + 1536);

    f32x16 acc0, acc1;
    #pragma unroll
    for (int r = 0; r < 16; ++r) { acc0[r] = 0.f; acc1[r] = 0.f; }
    float l_loc = 0.f;

    auto body = [&](bool diag, int buf) {
      short8 ka = *reinterpret_cast<const short8*>(&kvlds[buf][l*8]);
      short8 kb = *reinterpret_cast<const short8*>(&kvlds[buf][512 + l*8]);
      short8 kc = *reinterpret_cast<const short8*>(&kvlds[buf][1024 + l*8]);
      short8 kd = *reinterpret_cast<const short8*>(&kvlds[buf][1536 + l*8]);

      f32x16 s;
      #pragma unroll
      for (int r = 0; r < 16; ++r) s[r] = 0.f;
      __builtin_amdgcn_s_setprio(1);
      s = __builtin_amdgcn_mfma_f32_32x32x16_bf16(ka, qf0, s, 0, 0, 0);
      s = __builtin_amdgcn_mfma_f32_32x32x16_bf16(kb, qf1, s, 0, 0, 0);
      s = __builtin_amdgcn_mfma_f32_32x32x16_bf16(kc, qf2, s, 0, 0, 0);
      s = __builtin_amdgcn_mfma_f32_32x32x16_bf16(kd, qf3, s, 0, 0, 0);
      __builtin_amdgcn_s_setprio(0);

      if (diag) {
        #pragma unroll
        for (int r = 0; r < 16; ++r) {
          const int ko = (r & 3) + 8*(r >> 2) + 4*hi;
          s[r] = (ko <= lq) ? s[r] : -3.0e38f;
        }
      }

      unsigned int w8[8];
      float ps = 0.f;
      #pragma unroll
      for (int i = 0; i < 8; ++i) {
        float p0 = exp2f(s[2*i]);
        float p1 = exp2f(s[2*i+1]);
        ps += p0 + p1;
        asm("v_cvt_pk_bf16_f32 %0, %1, %2" : "=v"(w8[i]) : "v"(p0), "v"(p1));
      }
      l_loc += ps;                    // cross-lane reduction deferred to epilogue

      unsigned int x0 = w8[0], x1 = w8[1], y0 = w8[2], y1 = w8[3];
      asm("v_permlane32_swap_b32 %0, %1" : "+v"(x0), "+v"(y0));
      asm("v_permlane32_swap_b32 %0, %1" : "+v"(x1), "+v"(y1));
      unsigned int x2 = w8[4], x3 = w8[5], y2 = w8[6], y3 = w8[7];
      asm("v_permlane32_swap_b32 %0, %1" : "+v"(x2), "+v"(y2));
      asm("v_permlane32_swap_b32 %0, %1" : "+v"(x3), "+v"(y3));
      int4v p0i, p1i;
      p0i[0] = (int)x0; p0i[1] = (int)x1; p0i[2] = (int)y0; p0i[3] = (int)y1;
      p1i[0] = (int)x2; p1i[1] = (int)x3; p1i[2] = (int)y2; p1i[3] = (int)y3;
      short8 pa0 = __builtin_bit_cast(short8, p0i);
      short8 pa1 = __builtin_bit_cast(short8, p1i);

      short8 va = *reinterpret_cast<const short8*>(&kvlds[buf][2048 + l*8]);
      short8 vb = *reinterpret_cast<const short8*>(&kvlds[buf][2560 + l*8]);
      short8 vc = *reinterpret_cast<const short8*>(&kvlds[buf][3072 + l*8]);
      short8 vd = *reinterpret_cast<const short8*>(&kvlds[buf][3584 + l*8]);

      __builtin_amdgcn_s_setprio(1);
      acc0 = __builtin_amdgcn_mfma_f32_32x32x16_bf16(va, pa0, acc0, 0, 0, 0);
      acc0 = __builtin_amdgcn_mfma_f32_32x32x16_bf16(vb, pa1, acc0, 0, 0, 0);
      acc1 = __builtin_amdgcn_mfma_f32_32x32x16_bf16(vc, pa0, acc1, 0, 0, 0);
      acc1 = __builtin_amdgcn_mfma_f32_32x32x16_bf16(vd, pa1, acc1, 0, 0, 0);
      __builtin_amdgcn_s_setprio(0);
    };

    __syncthreads();                  // prior stream's LDS reads complete
    stage(0, 0);
    __syncthreads();
    for (int t = 0; ; ) {
      const int cur = t & 1;
      if (t < qt) stage(t + 1, cur ^ 1);
      body(t == qt, cur);
      if (++t > qt) break;
      __syncthreads();
    }

    const float l_run = l_loc + __shfl_xor(l_loc, 32);
    const float rl = 1.f / l_run;
    unsigned short* op = ctx + (size_t)(b*N_ + qt*32 + lq) * DOUT + h*HD_ + 4*hi;
    #pragma unroll
    for (int dt = 0; dt < 2; ++dt) {
      #pragma unroll
      for (int rq = 0; rq < 4; ++rq) {
        const float a0 = (dt ? acc1[4*rq+0] : acc0[4*rq+0]) * rl;
        const float a1 = (dt ? acc1[4*rq+1] : acc0[4*rq+1]) * rl;
        const float a2 = (dt ? acc1[4*rq+2] : acc0[4*rq+2]) * rl;
        const float a3 = (dt ? acc1[4*rq+3] : acc0[4*rq+3]) * rl;
        ushort4 st;
        st.x = f2bf(a0); st.y = f2bf(a1); st.z = f2bf(a2); st.w = f2bf(a3);
        *reinterpret_cast<ushort4*>(op + dt*32 + rq*8) = st;
      }
    }
  };

  process(pr);
  process(63 - pr);
}

// ---------------- launcher ----------------
extern "C" void kernel_launch(void* const* d_in, const int* in_sizes, int n_in,
                              void* d_out, int out_size, void* d_ws, size_t ws_size,
                              hipStream_t stream) {
  const float* x    = (const float*)d_in[0];
  const float* cosT = (const float*)d_in[1];
  const float* sinT = (const float*)d_in[2];
  const float* Wq   = (const float*)d_in[4];
  const float* Wk   = (const float*)d_in[5];
  const float* Wv   = (const float*)d_in[6];
  const float* Wo   = (const float*)d_in[7];
  float* out = (float*)d_out;

  char* ws = (char*)d_ws;
  unsigned short* xb     = (unsigned short*)(ws);              // 16.78 MB; reused as ctxb
  unsigned short* ctxb   = xb;
  unsigned short* Wqkv_t = (unsigned short*)(ws + 16777216);   // 12.58 MB (3072 x 2048)
  unsigned short* Wo_t   = (unsigned short*)(ws + 29360128);   //  8.39 MB
  unsigned short* Qp     = (unsigned short*)(ws + 37748736);   // 16.78 MB
  unsigned short* Kp     = (unsigned short*)(ws + 54525952);   //  4.19 MB
  unsigned short* Vp     = (unsigned short*)(ws + 58720256);   //  4.19 MB

  k_prep<<<dim3(288, 64), dim3(32, 8), 0, stream>>>(
      x, xb, Wq, Wk, Wv, Wo, Wqkv_t, Wo_t);

  k_gemm_qkv<<<dim3(3072/192, M_/256), 512, 0, stream>>>(
      xb, Wqkv_t, Qp, Kp, Vp, cosT, sinT);

  k_attn<<<dim3(512), dim3(256), 0, stream>>>(Qp, Kp, Vp, ctxb);

  k_gemm_out<<<dim3(DOUT/128, M_/256), 512, 0, stream>>>(ctxb, Wo_t, out);
}

// Round 20
// 164.778 us; speedup vs baseline: 1.0402x; 1.0402x over previous
//
#include <hip/hip_runtime.h>
#include <hip/hip_bf16.h>
#include <stdint.h>

#define B_   2
#define N_   2048
#define DIN  2048
#define DOUT 2048
#define H_   32
#define G_   8
#define HD_  64
#define M_   (B_*N_)   // 4096

using short8 = __attribute__((ext_vector_type(8))) short;
using f32x4  = __attribute__((ext_vector_type(4))) float;
using f32x16 = __attribute__((ext_vector_type(16))) float;
using int4v  = __attribute__((ext_vector_type(4))) int;

__device__ __forceinline__ unsigned short f2bf(float f) {
  unsigned int u = __float_as_uint(f);
  unsigned int r = u + 0x7FFFu + ((u >> 16) & 1u);
  return (unsigned short)(r >> 16);
}
__device__ __forceinline__ float bf2f(unsigned short h) {
  return __uint_as_float(((unsigned int)h) << 16);
}

// RoPE column permutation (involution): pairs (e,e+32) land 16 apart in aligned
// 32-col groups. p: [0,16)->id, [16,32)->+16, [32,48)->-16, [48,64)->id.
__device__ __forceinline__ int p63(int e) {
  return (((e >> 4) ^ (e >> 5)) & 1) ? (e ^ 48) : e;
}

// ---------------- merged x-cvt + weight transposes (one dispatch) ----------------
__global__ void k_prep(const float* __restrict__ x, unsigned short* __restrict__ xb,
                       const float* __restrict__ Wq, const float* __restrict__ Wk,
                       const float* __restrict__ Wv, const float* __restrict__ Wo,
                       unsigned short* __restrict__ Wqkv_t, unsigned short* __restrict__ Wo_t) {
  __shared__ float tile[32][33];
  const int ct = blockIdx.x;
  const int tx = threadIdx.x, ty = threadIdx.y;  // (32,8)
  if (ct >= 160) {
    const int i = ((ct - 160) * 64 + blockIdx.y) * 256 + ty * 32 + tx;
    float4 v = reinterpret_cast<const float4*>(x)[i];
    uint2 o;
    o.x = (unsigned int)f2bf(v.x) | ((unsigned int)f2bf(v.y) << 16);
    o.y = (unsigned int)f2bf(v.z) | ((unsigned int)f2bf(v.w) << 16);
    reinterpret_cast<uint2*>(xb)[i] = o;
    return;
  }
  const int r0 = blockIdx.y * 32;
  const float* W;
  unsigned short* dst;
  int C, c0, base, rope;
  if (ct < 64)      { W = Wq; dst = Wqkv_t; C = 2048; c0 = ct*32;      base = 0;    rope = 1; }
  else if (ct < 80) { W = Wk; dst = Wqkv_t; C = 512;  c0 = (ct-64)*32; base = 2048; rope = 1; }
  else if (ct < 96) { W = Wv; dst = Wqkv_t; C = 512;  c0 = (ct-80)*32; base = 2560; rope = 0; }
  else              { W = Wo; dst = Wo_t;   C = 2048; c0 = (ct-96)*32; base = 0;    rope = 0; }
  #pragma unroll
  for (int j = 0; j < 4; ++j)
    tile[ty + j*8][tx] = W[(size_t)(r0 + ty + j*8) * C + c0 + tx];
  __syncthreads();
  #pragma unroll
  for (int j = 0; j < 4; ++j) {
    int colW = c0 + ty + j*8;
    int row  = rope ? ((colW & ~63) | p63(colW & 63)) : colW;
    dst[(size_t)(base + row) * 2048 + r0 + tx] = f2bf(tile[tx][ty + j*8]);
  }
}

// ---------------- fused QKV GEMM, 256x192 8-phase (r18-proven) ----------------
#define QA0 0
#define QB0 32768
#define QA1 57344
#define QB1 90112

#define QP3(ABUF, M, STAGES, WAITS)                                              \
  {                                                                              \
    short8 a0 = rdA(ABUF, M, 0), a1 = rdA(ABUF, M, 1);                           \
    STAGES;                                                                      \
    WAITS;                                                                       \
    __builtin_amdgcn_s_barrier();                                                \
    asm volatile("s_waitcnt lgkmcnt(0)" ::: "memory");                           \
    __builtin_amdgcn_sched_barrier(0);                                           \
    __builtin_amdgcn_s_setprio(1);                                               \
    _Pragma("unroll")                                                            \
    for (int n = 0; n < 6; ++n) {                                                \
      acc[M][n] = __builtin_amdgcn_mfma_f32_16x16x32_bf16(a0, bv[n][0], acc[M][n], 0,0,0); \
      acc[M][n] = __builtin_amdgcn_mfma_f32_16x16x32_bf16(a1, bv[n][1], acc[M][n], 0,0,0); \
    }                                                                            \
    __builtin_amdgcn_s_setprio(0);                                               \
    __builtin_amdgcn_s_barrier();                                                \
  }

__global__ void __launch_bounds__(512, 2)
k_gemm_qkv(const unsigned short* __restrict__ A, const unsigned short* __restrict__ Bt,
           unsigned short* __restrict__ Qp, unsigned short* __restrict__ Kp,
           unsigned short* __restrict__ Vp,
           const float* __restrict__ cosT, const float* __restrict__ sinT) {
  __shared__ unsigned short sm[57344];     // 112 KiB: A0(32K)|B0(24K)|A1(32K)|B1(24K)
  const int tid = threadIdx.x;
  const int wid = tid >> 6, l = tid & 63;
  const int lrow = l & 15, lk = l >> 4;
  const int wm = wid >> 1, wn = wid & 1;   // wave grid 4 x 2

  const int gx   = gridDim.x;              // 16
  const int nwg  = gx * gridDim.y;         // 256
  const int orig = blockIdx.y * gx + blockIdx.x;
  const int q8   = nwg >> 3;
  const int xcd  = orig & 7, lin = orig >> 3;
  const int wg   = xcd * q8 + lin;
  const int bx   = wg % gx, by = wg / gx;
  const int rowA0 = by * 256, rowB0 = bx * 192;

  f32x4 acc[4][6];
  #pragma unroll
  for (int m = 0; m < 4; ++m)
    #pragma unroll
    for (int n = 0; n < 6; ++n)
      #pragma unroll
      for (int r = 0; r < 4; ++r) acc[m][n][r] = 0.f;

  const int srowoff = wid*8 + (l >> 3);
  const int skoff   = (((l & 7) ^ ((l >> 3) & 7)) << 3);   // inverse 3-bit swizzle
  auto stageU = [&](const unsigned short* Mat, int rowBase, int t, int bufByte, int u) {
    const unsigned short* g = Mat + (size_t)(rowBase + u*64 + srowoff) * 2048 + t*64 + skoff;
    __builtin_amdgcn_global_load_lds(
        (const __attribute__((address_space(1))) unsigned int*)g,
        (__attribute__((address_space(3))) unsigned int*)
            ((char*)sm + bufByte + u*8192 + wid*1024),
        16, 0, 0);
  };

  const int aswz = (lrow & 7) << 4;
  auto rdA = [&](int bufByte, int m, int kk) -> short8 {
    int byte = bufByte + (wm*64 + m*16 + lrow)*128 + ((kk*64 + lk*16) ^ aswz);
    return *reinterpret_cast<const short8*>((char*)sm + byte);
  };
  auto rdB = [&](int bufByte, int n, int kk) -> short8 {
    int byte = bufByte + (wn*96 + n*16 + lrow)*128 + ((kk*64 + lk*16) ^ aswz);
    return *reinterpret_cast<const short8*>((char*)sm + byte);
  };

  short8 bv[6][2];

  stageU(Bt, rowB0, 0, QB0, 0); stageU(Bt, rowB0, 0, QB0, 1); stageU(Bt, rowB0, 0, QB0, 2);
  stageU(A,  rowA0, 0, QA0, 0); stageU(A,  rowA0, 0, QA0, 1);
  stageU(A,  rowA0, 0, QA0, 2); stageU(A,  rowA0, 0, QA0, 3);
  stageU(Bt, rowB0, 1, QB1, 0); stageU(Bt, rowB0, 1, QB1, 1); stageU(Bt, rowB0, 1, QB1, 2);
  asm volatile("s_waitcnt vmcnt(3)" ::: "memory");
  __builtin_amdgcn_sched_barrier(0);
  __builtin_amdgcn_s_barrier();

  for (int i = 0; i < 16; ++i) {
    const int t = 2*i;
    const bool more = (i < 15);

    #pragma unroll
    for (int n = 0; n < 6; ++n) { bv[n][0] = rdB(QB0, n, 0); bv[n][1] = rdB(QB0, n, 1); }
    QP3(QA0, 0, { stageU(A, rowA0, t+1, QA1, 0); stageU(A, rowA0, t+1, QA1, 1); }, {});
    QP3(QA0, 1, { stageU(A, rowA0, t+1, QA1, 2); stageU(A, rowA0, t+1, QA1, 3); }, {});
    QP3(QA0, 2, { if (more) { stageU(Bt, rowB0, t+2, QB0, 0);
                              stageU(Bt, rowB0, t+2, QB0, 1); } }, {});
    QP3(QA0, 3, { if (more) stageU(Bt, rowB0, t+2, QB0, 2); },
                { if (more) { asm volatile("s_waitcnt vmcnt(3)" ::: "memory"); }
                  else      { asm volatile("s_waitcnt vmcnt(0)" ::: "memory"); }
                  __builtin_amdgcn_sched_barrier(0); });

    #pragma unroll
    for (int n = 0; n < 6; ++n) { bv[n][0] = rdB(QB1, n, 0); bv[n][1] = rdB(QB1, n, 1); }
    QP3(QA1, 0, { if (more) { stageU(A, rowA0, t+2, QA0, 0);
                              stageU(A, rowA0, t+2, QA0, 1); } }, {});
    QP3(QA1, 1, { if (more) { stageU(A, rowA0, t+2, QA0, 2);
                              stageU(A, rowA0, t+2, QA0, 3); } }, {});
    QP3(QA1, 2, { if (more) { stageU(Bt, rowB0, t+3, QB1, 0);
                              stageU(Bt, rowB0, t+3, QB1, 1); } }, {});
    QP3(QA1, 3, { if (more) stageU(Bt, rowB0, t+3, QB1, 2); },
                { if (more) { asm volatile("s_waitcnt vmcnt(3)" ::: "memory"); }
                  else      { asm volatile("s_waitcnt vmcnt(0)" ::: "memory"); }
                  __builtin_amdgcn_sched_barrier(0); });
  }

  // ---- epilogue: per 16-col fragment, classify Q/K/V (boundaries 32-aligned) ----
  #pragma unroll
  for (int m = 0; m < 4; ++m) {
    const int row0 = rowA0 + wm*64 + m*16 + lk*4;
    const int b    = row0 >> 11;
    const int key  = row0 & 2047;
    #pragma unroll
    for (int j = 0; j < 3; ++j) {
      const int col0 = rowB0 + wn*96 + j*32 + lrow;
      if (col0 >= 2560) {
        const size_t tbase = (size_t)(key >> 5)*2048 + (size_t)((key >> 4) & 1)*512
                           + (size_t)((key >> 3) & 1)*256 + (size_t)(key & 7);
        #pragma unroll
        for (int f = 0; f < 2; ++f) {
          const int cv = col0 + f*16 - 2560;
          const int gq = cv >> 6, d = cv & 63;
          const size_t addr = (size_t)(b*8 + gq)*131072 + tbase
                            + (size_t)(d >> 5)*1024 + (size_t)(d & 31)*8;
          ushort4 st;
          st.x = f2bf(acc[m][2*j+f][0]); st.y = f2bf(acc[m][2*j+f][1]);
          st.z = f2bf(acc[m][2*j+f][2]); st.w = f2bf(acc[m][2*j+f][3]);
          *reinterpret_cast<ushort4*>(Vp + addr) = st;
        }
      } else {
        const bool isQ = (col0 < 2048);
        const float scale = isQ ? 0.18033688011112042f : 1.0f;
        unsigned short* dst = isQ ? Qp : Kp;
        const int ch = col0 & 63;
        const int e  = ch - ((ch & 32) ? 16 : 0);
        const int hg = isQ ? (col0 >> 6) : ((col0 - 2048) >> 6);
        const size_t chunk = (size_t)(isQ ? (b*32 + hg) : (b*8 + hg)) * 64;
        #pragma unroll
        for (int r = 0; r < 4; ++r) {
          const int pos = key + r;
          const float cc = cosT[pos*64 + e] * scale;
          const float ss = sinT[pos*64 + e] * scale;
          const float x1 = acc[m][2*j][r];
          const float x2 = acc[m][2*j+1][r];
          const size_t off = (chunk + (pos >> 5)) * 2048
                           + (size_t)(e >> 4)*512 + (size_t)((e >> 3) & 1)*256
                           + (size_t)(pos & 31)*8 + (e & 7);
          dst[off]        = f2bf(x1*cc - x2*ss);
          dst[off + 1024] = f2bf(x2*cc + x1*ss);
        }
      }
    }
  }
}

// ---------------- output GEMM: ctx @ Wo^T -> f32, 256x128 8-phase (r17-proven) ----------------
#define OA0 0
#define OB0 32768
#define OA1 49152
#define OB1 81920

#define OPHASE(ABUF, M, STAGES, WAITS)                                           \
  {                                                                              \
    short8 a0 = rdA(ABUF, M, 0), a1 = rdA(ABUF, M, 1);                           \
    STAGES;                                                                      \
    WAITS;                                                                       \
    __builtin_amdgcn_s_barrier();                                                \
    asm volatile("s_waitcnt lgkmcnt(0)" ::: "memory");                           \
    __builtin_amdgcn_sched_barrier(0);                                           \
    __builtin_amdgcn_s_setprio(1);                                               \
    _Pragma("unroll")                                                            \
    for (int n = 0; n < 4; ++n) {                                                \
      acc[M][n] = __builtin_amdgcn_mfma_f32_16x16x32_bf16(a0, bv[n][0], acc[M][n], 0,0,0); \
      acc[M][n] = __builtin_amdgcn_mfma_f32_16x16x32_bf16(a1, bv[n][1], acc[M][n], 0,0,0); \
    }                                                                            \
    __builtin_amdgcn_s_setprio(0);                                               \
    __builtin_amdgcn_s_barrier();                                                \
  }

__global__ void __launch_bounds__(512, 2)
k_gemm_out(const unsigned short* __restrict__ A, const unsigned short* __restrict__ Bt,
           float* __restrict__ C) {
  __shared__ unsigned short sm[49152];     // 96 KiB
  const int tid = threadIdx.x;
  const int wid = tid >> 6, l = tid & 63;
  const int lrow = l & 15, lk = l >> 4;
  const int wm = wid >> 1, wn = wid & 1;   // wave grid 4 x 2

  const int gx   = gridDim.x;              // 16
  const int nwg  = gx * gridDim.y;         // 256
  const int orig = blockIdx.y * gx + blockIdx.x;
  const int q8   = nwg >> 3;
  const int xcd  = orig & 7, lin = orig >> 3;
  const int wg   = xcd * q8 + lin;
  const int bx   = wg % gx, by = wg / gx;
  const int rowA0 = by * 256, rowB0 = bx * 128;

  f32x4 acc[4][4];
  #pragma unroll
  for (int m = 0; m < 4; ++m)
    #pragma unroll
    for (int n = 0; n < 4; ++n)
      #pragma unroll
      for (int r = 0; r < 4; ++r) acc[m][n][r] = 0.f;

  const int srowoff = wid*8 + (l >> 3);
  const int skoff   = (((l & 7) ^ ((l >> 3) & 7)) << 3);
  auto stageU = [&](const unsigned short* Mat, int rowBase, int t, int bufByte, int u) {
    const unsigned short* g = Mat + (size_t)(rowBase + u*64 + srowoff) * 2048 + t*64 + skoff;
    __builtin_amdgcn_global_load_lds(
        (const __attribute__((address_space(1))) unsigned int*)g,
        (__attribute__((address_space(3))) unsigned int*)
            ((char*)sm + bufByte + u*8192 + wid*1024),
        16, 0, 0);
  };

  const int aswz = (lrow & 7) << 4;
  auto rdA = [&](int bufByte, int m, int kk) -> short8 {
    int byte = bufByte + (wm*64 + m*16 + lrow)*128 + ((kk*64 + lk*16) ^ aswz);
    return *reinterpret_cast<const short8*>((char*)sm + byte);
  };
  auto rdB = [&](int bufByte, int n, int kk) -> short8 {
    int byte = bufByte + (wn*64 + n*16 + lrow)*128 + ((kk*64 + lk*16) ^ aswz);
    return *reinterpret_cast<const short8*>((char*)sm + byte);
  };

  short8 bv[4][2];

  stageU(Bt, rowB0, 0, OB0, 0); stageU(Bt, rowB0, 0, OB0, 1);
  stageU(A,  rowA0, 0, OA0, 0); stageU(A,  rowA0, 0, OA0, 1);
  stageU(A,  rowA0, 0, OA0, 2); stageU(A,  rowA0, 0, OA0, 3);
  stageU(Bt, rowB0, 1, OB1, 0); stageU(Bt, rowB0, 1, OB1, 1);
  asm volatile("s_waitcnt vmcnt(2)" ::: "memory");
  __builtin_amdgcn_sched_barrier(0);
  __builtin_amdgcn_s_barrier();

  for (int i = 0; i < 16; ++i) {
    const int t = 2*i;
    const bool more = (i < 15);

    #pragma unroll
    for (int n = 0; n < 4; ++n) { bv[n][0] = rdB(OB0, n, 0); bv[n][1] = rdB(OB0, n, 1); }
    OPHASE(OA0, 0, { stageU(A, rowA0, t+1, OA1, 0); stageU(A, rowA0, t+1, OA1, 1); }, {});
    OPHASE(OA0, 1, { stageU(A, rowA0, t+1, OA1, 2); stageU(A, rowA0, t+1, OA1, 3); }, {});
    OPHASE(OA0, 2, { if (more) { stageU(Bt, rowB0, t+2, OB0, 0);
                                 stageU(Bt, rowB0, t+2, OB0, 1); } }, {});
    OPHASE(OA0, 3, {}, { if (more) { asm volatile("s_waitcnt vmcnt(2)" ::: "memory"); }
                         else      { asm volatile("s_waitcnt vmcnt(0)" ::: "memory"); }
                         __builtin_amdgcn_sched_barrier(0); });

    #pragma unroll
    for (int n = 0; n < 4; ++n) { bv[n][0] = rdB(OB1, n, 0); bv[n][1] = rdB(OB1, n, 1); }
    OPHASE(OA1, 0, { if (more) { stageU(A, rowA0, t+2, OA0, 0);
                                 stageU(A, rowA0, t+2, OA0, 1); } }, {});
    OPHASE(OA1, 1, { if (more) { stageU(A, rowA0, t+2, OA0, 2);
                                 stageU(A, rowA0, t+2, OA0, 3); } }, {});
    OPHASE(OA1, 2, { if (more) { stageU(Bt, rowB0, t+3, OB1, 0);
                                 stageU(Bt, rowB0, t+3, OB1, 1); } }, {});
    OPHASE(OA1, 3, {}, { if (more) { asm volatile("s_waitcnt vmcnt(2)" ::: "memory"); }
                         else      { asm volatile("s_waitcnt vmcnt(0)" ::: "memory"); }
                         __builtin_amdgcn_sched_barrier(0); });
  }

  #pragma unroll
  for (int m = 0; m < 4; ++m) {
    int row0 = rowA0 + wm*64 + m*16 + lk*4;
    #pragma unroll
    for (int n = 0; n < 4; ++n) {
      int col = rowB0 + wn*64 + n*16 + lrow;
      #pragma unroll
      for (int r = 0; r < 4; ++r)
        C[(size_t)(row0 + r) * DOUT + col] = acc[m][n][r];
    }
  }
}

// ---------------- causal GQA flash attention (r18 structure; launch_bounds(256,4)) ----------------
// r20: bound raised 3->4 waves/SIMD so all FOUR complementary blocks of the
// balanced qt map {63-x, 32+x, 31-x, x} are co-resident per CU (sum 126 = no
// imbalance, no tail). Fixed-max softmax; l-shuffle deferred to epilogue.
__global__ void __launch_bounds__(256, 4)
k_attn(const unsigned short* __restrict__ Qp, const unsigned short* __restrict__ Kp,
       const unsigned short* __restrict__ Vp, unsigned short* __restrict__ ctx) {
  __shared__ unsigned short kvlds[2][4096];   // [buf][ K:0..2047 | V:2048..4095 ]
  const int bid = blockIdx.x;            // 0..1023
  const int c   = bid & 15;              // (b,g) chunk -> fixed XCD
  const int b   = c >> 3, g = c & 7;
  const int w   = bid >> 4;              // 0..63
  const int jj  = w >> 4, x = w & 15;
  const int qt  = (jj == 0) ? 63 - x : (jj == 1) ? 32 + x : (jj == 2) ? 31 - x : x;
  const int tid = threadIdx.x;
  const int hh  = tid >> 6;              // wave id = head within group
  const int h   = g*4 + hh;
  const int l   = tid & 63;
  const int lq  = l & 31, hi = l >> 5;

  const unsigned short* qbase = Qp + ((size_t)(b*32 + h)*64 + qt)*2048 + l*8;
  short8 qf0 = *reinterpret_cast<const short8*>(qbase);
  short8 qf1 = *reinterpret_cast<const short8*>(qbase + 512);
  short8 qf2 = *reinterpret_cast<const short8*>(qbase + 1024);
  short8 qf3 = *reinterpret_cast<const short8*>(qbase + 1536);

  const unsigned short* ksrc = Kp + (size_t)c*131072 + hh*512 + l*8;
  const unsigned short* vsrc = Vp + (size_t)c*131072 + hh*512 + l*8;

  f32x16 acc0, acc1;
  #pragma unroll
  for (int r = 0; r < 16; ++r) { acc0[r] = 0.f; acc1[r] = 0.f; }
  float l_loc = 0.f;

  auto stage = [&](int t, int buf) {
    __builtin_amdgcn_global_load_lds(
        (const __attribute__((address_space(1))) unsigned int*)(ksrc + (size_t)t*2048),
        (__attribute__((address_space(3))) unsigned int*)((char*)&kvlds[buf][0] + hh*1024),
        16, 0, 0);
    __builtin_amdgcn_global_load_lds(
        (const __attribute__((address_space(1))) unsigned int*)(vsrc + (size_t)t*2048),
        (__attribute__((address_space(3))) unsigned int*)((char*)&kvlds[buf][2048] + hh*1024),
        16, 0, 0);
  };

  auto body = [&](bool diag, int buf) {
    short8 ka = *reinterpret_cast<const short8*>(&kvlds[buf][l*8]);
    short8 kb = *reinterpret_cast<const short8*>(&kvlds[buf][512 + l*8]);
    short8 kc = *reinterpret_cast<const short8*>(&kvlds[buf][1024 + l*8]);
    short8 kd = *reinterpret_cast<const short8*>(&kvlds[buf][1536 + l*8]);

    f32x16 s;
    #pragma unroll
    for (int r = 0; r < 16; ++r) s[r] = 0.f;
    __builtin_amdgcn_s_setprio(1);
    s = __builtin_amdgcn_mfma_f32_32x32x16_bf16(ka, qf0, s, 0, 0, 0);
    s = __builtin_amdgcn_mfma_f32_32x32x16_bf16(kb, qf1, s, 0, 0, 0);
    s = __builtin_amdgcn_mfma_f32_32x32x16_bf16(kc, qf2, s, 0, 0, 0);
    s = __builtin_amdgcn_mfma_f32_32x32x16_bf16(kd, qf3, s, 0, 0, 0);
    __builtin_amdgcn_s_setprio(0);

    if (diag) {
      #pragma unroll
      for (int r = 0; r < 16; ++r) {
        const int ko = (r & 3) + 8*(r >> 2) + 4*hi;
        s[r] = (ko <= lq) ? s[r] : -3.0e38f;
      }
    }

    unsigned int w8[8];
    float ps = 0.f;
    #pragma unroll
    for (int i = 0; i < 8; ++i) {
      float p0 = exp2f(s[2*i]);
      float p1 = exp2f(s[2*i+1]);
      ps += p0 + p1;
      asm("v_cvt_pk_bf16_f32 %0, %1, %2" : "=v"(w8[i]) : "v"(p0), "v"(p1));
    }
    l_loc += ps;                      // cross-lane reduction deferred to epilogue

    unsigned int x0 = w8[0], x1 = w8[1], y0 = w8[2], y1 = w8[3];
    asm("v_permlane32_swap_b32 %0, %1" : "+v"(x0), "+v"(y0));
    asm("v_permlane32_swap_b32 %0, %1" : "+v"(x1), "+v"(y1));
    unsigned int x2 = w8[4], x3 = w8[5], y2 = w8[6], y3 = w8[7];
    asm("v_permlane32_swap_b32 %0, %1" : "+v"(x2), "+v"(y2));
    asm("v_permlane32_swap_b32 %0, %1" : "+v"(x3), "+v"(y3));
    int4v p0i, p1i;
    p0i[0] = (int)x0; p0i[1] = (int)x1; p0i[2] = (int)y0; p0i[3] = (int)y1;
    p1i[0] = (int)x2; p1i[1] = (int)x3; p1i[2] = (int)y2; p1i[3] = (int)y3;
    short8 pa0 = __builtin_bit_cast(short8, p0i);
    short8 pa1 = __builtin_bit_cast(short8, p1i);

    short8 va = *reinterpret_cast<const short8*>(&kvlds[buf][2048 + l*8]);
    short8 vb = *reinterpret_cast<const short8*>(&kvlds[buf][2560 + l*8]);
    short8 vc = *reinterpret_cast<const short8*>(&kvlds[buf][3072 + l*8]);
    short8 vd = *reinterpret_cast<const short8*>(&kvlds[buf][3584 + l*8]);

    __builtin_amdgcn_s_setprio(1);
    acc0 = __builtin_amdgcn_mfma_f32_32x32x16_bf16(va, pa0, acc0, 0, 0, 0);
    acc0 = __builtin_amdgcn_mfma_f32_32x32x16_bf16(vb, pa1, acc0, 0, 0, 0);
    acc1 = __builtin_amdgcn_mfma_f32_32x32x16_bf16(vc, pa0, acc1, 0, 0, 0);
    acc1 = __builtin_amdgcn_mfma_f32_32x32x16_bf16(vd, pa1, acc1, 0, 0, 0);
    __builtin_amdgcn_s_setprio(0);
  };

  stage(0, 0);
  __syncthreads();
  for (int t = 0; ; ) {
    const int cur = t & 1;
    if (t < qt) stage(t + 1, cur ^ 1);
    body(t == qt, cur);
    if (++t > qt) break;
    __syncthreads();
  }

  const float l_run = l_loc + __shfl_xor(l_loc, 32);
  const float rl = 1.f / l_run;
  unsigned short* op = ctx + (size_t)(b*N_ + qt*32 + lq) * DOUT + h*HD_ + 4*hi;
  #pragma unroll
  for (int dt = 0; dt < 2; ++dt) {
    #pragma unroll
    for (int rq = 0; rq < 4; ++rq) {
      const float a0 = (dt ? acc1[4*rq+0] : acc0[4*rq+0]) * rl;
      const float a1 = (dt ? acc1[4*rq+1] : acc0[4*rq+1]) * rl;
      const float a2 = (dt ? acc1[4*rq+2] : acc0[4*rq+2]) * rl;
      const float a3 = (dt ? acc1[4*rq+3] : acc0[4*rq+3]) * rl;
      ushort4 st;
      st.x = f2bf(a0); st.y = f2bf(a1); st.z = f2bf(a2); st.w = f2bf(a3);
      *reinterpret_cast<ushort4*>(op + dt*32 + rq*8) = st;
    }
  }
}

// ---------------- launcher ----------------
extern "C" void kernel_launch(void* const* d_in, const int* in_sizes, int n_in,
                              void* d_out, int out_size, void* d_ws, size_t ws_size,
                              hipStream_t stream) {
  const float* x    = (const float*)d_in[0];
  const float* cosT = (const float*)d_in[1];
  const float* sinT = (const float*)d_in[2];
  const float* Wq   = (const float*)d_in[4];
  const float* Wk   = (const float*)d_in[5];
  const float* Wv   = (const float*)d_in[6];
  const float* Wo   = (const float*)d_in[7];
  float* out = (float*)d_out;

  char* ws = (char*)d_ws;
  unsigned short* xb     = (unsigned short*)(ws);              // 16.78 MB; reused as ctxb
  unsigned short* ctxb   = xb;
  unsigned short* Wqkv_t = (unsigned short*)(ws + 16777216);   // 12.58 MB (3072 x 2048)
  unsigned short* Wo_t   = (unsigned short*)(ws + 29360128);   //  8.39 MB
  unsigned short* Qp     = (unsigned short*)(ws + 37748736);   // 16.78 MB
  unsigned short* Kp     = (unsigned short*)(ws + 54525952);   //  4.19 MB
  unsigned short* Vp     = (unsigned short*)(ws + 58720256);   //  4.19 MB

  k_prep<<<dim3(288, 64), dim3(32, 8), 0, stream>>>(
      x, xb, Wq, Wk, Wv, Wo, Wqkv_t, Wo_t);

  k_gemm_qkv<<<dim3(3072/192, M_/256), 512, 0, stream>>>(
      xb, Wqkv_t, Qp, Kp, Vp, cosT, sinT);

  k_attn<<<dim3(1024), dim3(256), 0, stream>>>(Qp, Kp, Vp, ctxb);

  k_gemm_out<<<dim3(DOUT/128, M_/256), 512, 0, stream>>>(ctxb, Wo_t, out);
}

// Round 21
// 163.306 us; speedup vs baseline: 1.0496x; 1.0090x over previous
//
#include <hip/hip_runtime.h>
#include <hip/hip_bf16.h>
#include <stdint.h>

#define B_   2
#define N_   2048
#define DIN  2048
#define DOUT 2048
#define H_   32
#define G_   8
#define HD_  64
#define M_   (B_*N_)   // 4096

using short8 = __attribute__((ext_vector_type(8))) short;
using f32x4  = __attribute__((ext_vector_type(4))) float;
using f32x16 = __attribute__((ext_vector_type(16))) float;
using int4v  = __attribute__((ext_vector_type(4))) int;

__device__ __forceinline__ unsigned short f2bf(float f) {
  unsigned int u = __float_as_uint(f);
  unsigned int r = u + 0x7FFFu + ((u >> 16) & 1u);
  return (unsigned short)(r >> 16);
}
__device__ __forceinline__ float bf2f(unsigned short h) {
  return __uint_as_float(((unsigned int)h) << 16);
}

// RoPE column permutation (involution): pairs (e,e+32) land 16 apart in aligned
// 32-col groups. p: [0,16)->id, [16,32)->+16, [32,48)->-16, [48,64)->id.
__device__ __forceinline__ int p63(int e) {
  return (((e >> 4) ^ (e >> 5)) & 1) ? (e ^ 48) : e;
}

// ---------------- merged x-cvt + weight transposes (one dispatch) ----------------
__global__ void k_prep(const float* __restrict__ x, unsigned short* __restrict__ xb,
                       const float* __restrict__ Wq, const float* __restrict__ Wk,
                       const float* __restrict__ Wv, const float* __restrict__ Wo,
                       unsigned short* __restrict__ Wqkv_t, unsigned short* __restrict__ Wo_t) {
  __shared__ float tile[32][33];
  const int ct = blockIdx.x;
  const int tx = threadIdx.x, ty = threadIdx.y;  // (32,8)
  if (ct >= 160) {
    const int i = ((ct - 160) * 64 + blockIdx.y) * 256 + ty * 32 + tx;
    float4 v = reinterpret_cast<const float4*>(x)[i];
    uint2 o;
    o.x = (unsigned int)f2bf(v.x) | ((unsigned int)f2bf(v.y) << 16);
    o.y = (unsigned int)f2bf(v.z) | ((unsigned int)f2bf(v.w) << 16);
    reinterpret_cast<uint2*>(xb)[i] = o;
    return;
  }
  const int r0 = blockIdx.y * 32;
  const float* W;
  unsigned short* dst;
  int C, c0, base, rope;
  if (ct < 64)      { W = Wq; dst = Wqkv_t; C = 2048; c0 = ct*32;      base = 0;    rope = 1; }
  else if (ct < 80) { W = Wk; dst = Wqkv_t; C = 512;  c0 = (ct-64)*32; base = 2048; rope = 1; }
  else if (ct < 96) { W = Wv; dst = Wqkv_t; C = 512;  c0 = (ct-80)*32; base = 2560; rope = 0; }
  else              { W = Wo; dst = Wo_t;   C = 2048; c0 = (ct-96)*32; base = 0;    rope = 0; }
  #pragma unroll
  for (int j = 0; j < 4; ++j)
    tile[ty + j*8][tx] = W[(size_t)(r0 + ty + j*8) * C + c0 + tx];
  __syncthreads();
  #pragma unroll
  for (int j = 0; j < 4; ++j) {
    int colW = c0 + ty + j*8;
    int row  = rope ? ((colW & ~63) | p63(colW & 63)) : colW;
    dst[(size_t)(base + row) * 2048 + r0 + tx] = f2bf(tile[tx][ty + j*8]);
  }
}

// ---------------- fused QKV GEMM, 256x192, FUSED 4-phase (r21) ----------------
// Phase pairs merged: 4 A ds_reads + 24 MFMAs per barrier pair (was 2+12).
// Ledger: gate at end of each K-tile's fused pair; outstanding = A(next)4 + B(next2)3
// -> vmcnt(3) proves A landed. Same WAR separation as the r18-proven schedule.
#define QA0 0
#define QB0 32768
#define QA1 57344
#define QB1 90112

#define QPF(ABUF, M0, STAGES, WAITS)                                             \
  {                                                                              \
    short8 a00 = rdA(ABUF, M0, 0),   a01 = rdA(ABUF, M0, 1);                     \
    short8 a10 = rdA(ABUF, M0+1, 0), a11 = rdA(ABUF, M0+1, 1);                   \
    STAGES;                                                                      \
    WAITS;                                                                       \
    __builtin_amdgcn_s_barrier();                                                \
    asm volatile("s_waitcnt lgkmcnt(0)" ::: "memory");                           \
    __builtin_amdgcn_sched_barrier(0);                                           \
    __builtin_amdgcn_s_setprio(1);                                               \
    _Pragma("unroll")                                                            \
    for (int n = 0; n < 6; ++n) {                                                \
      acc[M0][n]   = __builtin_amdgcn_mfma_f32_16x16x32_bf16(a00, bv[n][0], acc[M0][n], 0,0,0);   \
      acc[M0][n]   = __builtin_amdgcn_mfma_f32_16x16x32_bf16(a01, bv[n][1], acc[M0][n], 0,0,0);   \
      acc[M0+1][n] = __builtin_amdgcn_mfma_f32_16x16x32_bf16(a10, bv[n][0], acc[M0+1][n], 0,0,0); \
      acc[M0+1][n] = __builtin_amdgcn_mfma_f32_16x16x32_bf16(a11, bv[n][1], acc[M0+1][n], 0,0,0); \
    }                                                                            \
    __builtin_amdgcn_s_setprio(0);                                               \
    __builtin_amdgcn_s_barrier();                                                \
  }

__global__ void __launch_bounds__(512, 2)
k_gemm_qkv(const unsigned short* __restrict__ A, const unsigned short* __restrict__ Bt,
           unsigned short* __restrict__ Qp, unsigned short* __restrict__ Kp,
           unsigned short* __restrict__ Vp,
           const float* __restrict__ cosT, const float* __restrict__ sinT) {
  __shared__ unsigned short sm[57344];     // 112 KiB: A0(32K)|B0(24K)|A1(32K)|B1(24K)
  const int tid = threadIdx.x;
  const int wid = tid >> 6, l = tid & 63;
  const int lrow = l & 15, lk = l >> 4;
  const int wm = wid >> 1, wn = wid & 1;   // wave grid 4 x 2

  const int gx   = gridDim.x;              // 16
  const int nwg  = gx * gridDim.y;         // 256
  const int orig = blockIdx.y * gx + blockIdx.x;
  const int q8   = nwg >> 3;
  const int xcd  = orig & 7, lin = orig >> 3;
  const int wg   = xcd * q8 + lin;
  const int bx   = wg % gx, by = wg / gx;
  const int rowA0 = by * 256, rowB0 = bx * 192;

  f32x4 acc[4][6];
  #pragma unroll
  for (int m = 0; m < 4; ++m)
    #pragma unroll
    for (int n = 0; n < 6; ++n)
      #pragma unroll
      for (int r = 0; r < 4; ++r) acc[m][n][r] = 0.f;

  const int srowoff = wid*8 + (l >> 3);
  const int skoff   = (((l & 7) ^ ((l >> 3) & 7)) << 3);   // inverse 3-bit swizzle
  auto stageU = [&](const unsigned short* Mat, int rowBase, int t, int bufByte, int u) {
    const unsigned short* g = Mat + (size_t)(rowBase + u*64 + srowoff) * 2048 + t*64 + skoff;
    __builtin_amdgcn_global_load_lds(
        (const __attribute__((address_space(1))) unsigned int*)g,
        (__attribute__((address_space(3))) unsigned int*)
            ((char*)sm + bufByte + u*8192 + wid*1024),
        16, 0, 0);
  };

  const int aswz = (lrow & 7) << 4;
  auto rdA = [&](int bufByte, int m, int kk) -> short8 {
    int byte = bufByte + (wm*64 + m*16 + lrow)*128 + ((kk*64 + lk*16) ^ aswz);
    return *reinterpret_cast<const short8*>((char*)sm + byte);
  };
  auto rdB = [&](int bufByte, int n, int kk) -> short8 {
    int byte = bufByte + (wn*96 + n*16 + lrow)*128 + ((kk*64 + lk*16) ^ aswz);
    return *reinterpret_cast<const short8*>((char*)sm + byte);
  };

  short8 bv[6][2];

  stageU(Bt, rowB0, 0, QB0, 0); stageU(Bt, rowB0, 0, QB0, 1); stageU(Bt, rowB0, 0, QB0, 2);
  stageU(A,  rowA0, 0, QA0, 0); stageU(A,  rowA0, 0, QA0, 1);
  stageU(A,  rowA0, 0, QA0, 2); stageU(A,  rowA0, 0, QA0, 3);
  stageU(Bt, rowB0, 1, QB1, 0); stageU(Bt, rowB0, 1, QB1, 1); stageU(Bt, rowB0, 1, QB1, 2);
  asm volatile("s_waitcnt vmcnt(3)" ::: "memory");
  __builtin_amdgcn_sched_barrier(0);
  __builtin_amdgcn_s_barrier();

  for (int i = 0; i < 16; ++i) {
    const int t = 2*i;
    const bool more = (i < 15);

    #pragma unroll
    for (int n = 0; n < 6; ++n) { bv[n][0] = rdB(QB0, n, 0); bv[n][1] = rdB(QB0, n, 1); }
    QPF(QA0, 0, { stageU(A, rowA0, t+1, QA1, 0); stageU(A, rowA0, t+1, QA1, 1);
                  stageU(A, rowA0, t+1, QA1, 2); stageU(A, rowA0, t+1, QA1, 3); }, {});
    QPF(QA0, 2, { if (more) { stageU(Bt, rowB0, t+2, QB0, 0);
                              stageU(Bt, rowB0, t+2, QB0, 1);
                              stageU(Bt, rowB0, t+2, QB0, 2); } },
                { if (more) { asm volatile("s_waitcnt vmcnt(3)" ::: "memory"); }
                  else      { asm volatile("s_waitcnt vmcnt(0)" ::: "memory"); }
                  __builtin_amdgcn_sched_barrier(0); });

    #pragma unroll
    for (int n = 0; n < 6; ++n) { bv[n][0] = rdB(QB1, n, 0); bv[n][1] = rdB(QB1, n, 1); }
    QPF(QA1, 0, { if (more) { stageU(A, rowA0, t+2, QA0, 0); stageU(A, rowA0, t+2, QA0, 1);
                              stageU(A, rowA0, t+2, QA0, 2); stageU(A, rowA0, t+2, QA0, 3); } }, {});
    QPF(QA1, 2, { if (more) { stageU(Bt, rowB0, t+3, QB1, 0);
                              stageU(Bt, rowB0, t+3, QB1, 1);
                              stageU(Bt, rowB0, t+3, QB1, 2); } },
                { if (more) { asm volatile("s_waitcnt vmcnt(3)" ::: "memory"); }
                  else      { asm volatile("s_waitcnt vmcnt(0)" ::: "memory"); }
                  __builtin_amdgcn_sched_barrier(0); });
  }

  // ---- epilogue: per 16-col fragment, classify Q/K/V (boundaries 32-aligned) ----
  #pragma unroll
  for (int m = 0; m < 4; ++m) {
    const int row0 = rowA0 + wm*64 + m*16 + lk*4;
    const int b    = row0 >> 11;
    const int key  = row0 & 2047;
    #pragma unroll
    for (int j = 0; j < 3; ++j) {
      const int col0 = rowB0 + wn*96 + j*32 + lrow;
      if (col0 >= 2560) {
        const size_t tbase = (size_t)(key >> 5)*2048 + (size_t)((key >> 4) & 1)*512
                           + (size_t)((key >> 3) & 1)*256 + (size_t)(key & 7);
        #pragma unroll
        for (int f = 0; f < 2; ++f) {
          const int cv = col0 + f*16 - 2560;
          const int gq = cv >> 6, d = cv & 63;
          const size_t addr = (size_t)(b*8 + gq)*131072 + tbase
                            + (size_t)(d >> 5)*1024 + (size_t)(d & 31)*8;
          ushort4 st;
          st.x = f2bf(acc[m][2*j+f][0]); st.y = f2bf(acc[m][2*j+f][1]);
          st.z = f2bf(acc[m][2*j+f][2]); st.w = f2bf(acc[m][2*j+f][3]);
          *reinterpret_cast<ushort4*>(Vp + addr) = st;
        }
      } else {
        const bool isQ = (col0 < 2048);
        const float scale = isQ ? 0.18033688011112042f : 1.0f;
        unsigned short* dst = isQ ? Qp : Kp;
        const int ch = col0 & 63;
        const int e  = ch - ((ch & 32) ? 16 : 0);
        const int hg = isQ ? (col0 >> 6) : ((col0 - 2048) >> 6);
        const size_t chunk = (size_t)(isQ ? (b*32 + hg) : (b*8 + hg)) * 64;
        #pragma unroll
        for (int r = 0; r < 4; ++r) {
          const int pos = key + r;
          const float cc = cosT[pos*64 + e] * scale;
          const float ss = sinT[pos*64 + e] * scale;
          const float x1 = acc[m][2*j][r];
          const float x2 = acc[m][2*j+1][r];
          const size_t off = (chunk + (pos >> 5)) * 2048
                           + (size_t)(e >> 4)*512 + (size_t)((e >> 3) & 1)*256
                           + (size_t)(pos & 31)*8 + (e & 7);
          dst[off]        = f2bf(x1*cc - x2*ss);
          dst[off + 1024] = f2bf(x2*cc + x1*ss);
        }
      }
    }
  }
}

// ---------------- output GEMM: ctx @ Wo^T -> f32, 256x128, FUSED 4-phase ----------------
#define OA0 0
#define OB0 32768
#define OA1 49152
#define OB1 81920

#define OPF(ABUF, M0, STAGES, WAITS)                                             \
  {                                                                              \
    short8 a00 = rdA(ABUF, M0, 0),   a01 = rdA(ABUF, M0, 1);                     \
    short8 a10 = rdA(ABUF, M0+1, 0), a11 = rdA(ABUF, M0+1, 1);                   \
    STAGES;                                                                      \
    WAITS;                                                                       \
    __builtin_amdgcn_s_barrier();                                                \
    asm volatile("s_waitcnt lgkmcnt(0)" ::: "memory");                           \
    __builtin_amdgcn_sched_barrier(0);                                           \
    __builtin_amdgcn_s_setprio(1);                                               \
    _Pragma("unroll")                                                            \
    for (int n = 0; n < 4; ++n) {                                                \
      acc[M0][n]   = __builtin_amdgcn_mfma_f32_16x16x32_bf16(a00, bv[n][0], acc[M0][n], 0,0,0);   \
      acc[M0][n]   = __builtin_amdgcn_mfma_f32_16x16x32_bf16(a01, bv[n][1], acc[M0][n], 0,0,0);   \
      acc[M0+1][n] = __builtin_amdgcn_mfma_f32_16x16x32_bf16(a10, bv[n][0], acc[M0+1][n], 0,0,0); \
      acc[M0+1][n] = __builtin_amdgcn_mfma_f32_16x16x32_bf16(a11, bv[n][1], acc[M0+1][n], 0,0,0); \
    }                                                                            \
    __builtin_amdgcn_s_setprio(0);                                               \
    __builtin_amdgcn_s_barrier();                                                \
  }

__global__ void __launch_bounds__(512, 2)
k_gemm_out(const unsigned short* __restrict__ A, const unsigned short* __restrict__ Bt,
           float* __restrict__ C) {
  __shared__ unsigned short sm[49152];     // 96 KiB
  const int tid = threadIdx.x;
  const int wid = tid >> 6, l = tid & 63;
  const int lrow = l & 15, lk = l >> 4;
  const int wm = wid >> 1, wn = wid & 1;   // wave grid 4 x 2

  const int gx   = gridDim.x;              // 16
  const int nwg  = gx * gridDim.y;         // 256
  const int orig = blockIdx.y * gx + blockIdx.x;
  const int q8   = nwg >> 3;
  const int xcd  = orig & 7, lin = orig >> 3;
  const int wg   = xcd * q8 + lin;
  const int bx   = wg % gx, by = wg / gx;
  const int rowA0 = by * 256, rowB0 = bx * 128;

  f32x4 acc[4][4];
  #pragma unroll
  for (int m = 0; m < 4; ++m)
    #pragma unroll
    for (int n = 0; n < 4; ++n)
      #pragma unroll
      for (int r = 0; r < 4; ++r) acc[m][n][r] = 0.f;

  const int srowoff = wid*8 + (l >> 3);
  const int skoff   = (((l & 7) ^ ((l >> 3) & 7)) << 3);
  auto stageU = [&](const unsigned short* Mat, int rowBase, int t, int bufByte, int u) {
    const unsigned short* g = Mat + (size_t)(rowBase + u*64 + srowoff) * 2048 + t*64 + skoff;
    __builtin_amdgcn_global_load_lds(
        (const __attribute__((address_space(1))) unsigned int*)g,
        (__attribute__((address_space(3))) unsigned int*)
            ((char*)sm + bufByte + u*8192 + wid*1024),
        16, 0, 0);
  };

  const int aswz = (lrow & 7) << 4;
  auto rdA = [&](int bufByte, int m, int kk) -> short8 {
    int byte = bufByte + (wm*64 + m*16 + lrow)*128 + ((kk*64 + lk*16) ^ aswz);
    return *reinterpret_cast<const short8*>((char*)sm + byte);
  };
  auto rdB = [&](int bufByte, int n, int kk) -> short8 {
    int byte = bufByte + (wn*64 + n*16 + lrow)*128 + ((kk*64 + lk*16) ^ aswz);
    return *reinterpret_cast<const short8*>((char*)sm + byte);
  };

  short8 bv[4][2];

  stageU(Bt, rowB0, 0, OB0, 0); stageU(Bt, rowB0, 0, OB0, 1);
  stageU(A,  rowA0, 0, OA0, 0); stageU(A,  rowA0, 0, OA0, 1);
  stageU(A,  rowA0, 0, OA0, 2); stageU(A,  rowA0, 0, OA0, 3);
  stageU(Bt, rowB0, 1, OB1, 0); stageU(Bt, rowB0, 1, OB1, 1);
  asm volatile("s_waitcnt vmcnt(2)" ::: "memory");
  __builtin_amdgcn_sched_barrier(0);
  __builtin_amdgcn_s_barrier();

  for (int i = 0; i < 16; ++i) {
    const int t = 2*i;
    const bool more = (i < 15);

    #pragma unroll
    for (int n = 0; n < 4; ++n) { bv[n][0] = rdB(OB0, n, 0); bv[n][1] = rdB(OB0, n, 1); }
    OPF(OA0, 0, { stageU(A, rowA0, t+1, OA1, 0); stageU(A, rowA0, t+1, OA1, 1);
                  stageU(A, rowA0, t+1, OA1, 2); stageU(A, rowA0, t+1, OA1, 3); }, {});
    OPF(OA0, 2, { if (more) { stageU(Bt, rowB0, t+2, OB0, 0);
                              stageU(Bt, rowB0, t+2, OB0, 1); } },
                { if (more) { asm volatile("s_waitcnt vmcnt(2)" ::: "memory"); }
                  else      { asm volatile("s_waitcnt vmcnt(0)" ::: "memory"); }
                  __builtin_amdgcn_sched_barrier(0); });

    #pragma unroll
    for (int n = 0; n < 4; ++n) { bv[n][0] = rdB(OB1, n, 0); bv[n][1] = rdB(OB1, n, 1); }
    OPF(OA1, 0, { if (more) { stageU(A, rowA0, t+2, OA0, 0); stageU(A, rowA0, t+2, OA0, 1);
                              stageU(A, rowA0, t+2, OA0, 2); stageU(A, rowA0, t+2, OA0, 3); } }, {});
    OPF(OA1, 2, { if (more) { stageU(Bt, rowB0, t+3, OB1, 0);
                              stageU(Bt, rowB0, t+3, OB1, 1); } },
                { if (more) { asm volatile("s_waitcnt vmcnt(2)" ::: "memory"); }
                  else      { asm volatile("s_waitcnt vmcnt(0)" ::: "memory"); }
                  __builtin_amdgcn_sched_barrier(0); });
  }

  #pragma unroll
  for (int m = 0; m < 4; ++m) {
    int row0 = rowA0 + wm*64 + m*16 + lk*4;
    #pragma unroll
    for (int n = 0; n < 4; ++n) {
      int col = rowB0 + wn*64 + n*16 + lrow;
      #pragma unroll
      for (int r = 0; r < 4; ++r)
        C[(size_t)(row0 + r) * DOUT + col] = acc[m][n][r];
    }
  }
}

// ---------------- causal GQA flash attention (r20-proven, unchanged) ----------------
__global__ void __launch_bounds__(256, 4)
k_attn(const unsigned short* __restrict__ Qp, const unsigned short* __restrict__ Kp,
       const unsigned short* __restrict__ Vp, unsigned short* __restrict__ ctx) {
  __shared__ unsigned short kvlds[2][4096];   // [buf][ K:0..2047 | V:2048..4095 ]
  const int bid = blockIdx.x;            // 0..1023
  const int c   = bid & 15;              // (b,g) chunk -> fixed XCD
  const int b   = c >> 3, g = c & 7;
  const int w   = bid >> 4;              // 0..63
  const int jj  = w >> 4, x = w & 15;
  const int qt  = (jj == 0) ? 63 - x : (jj == 1) ? 32 + x : (jj == 2) ? 31 - x : x;
  const int tid = threadIdx.x;
  const int hh  = tid >> 6;              // wave id = head within group
  const int h   = g*4 + hh;
  const int l   = tid & 63;
  const int lq  = l & 31, hi = l >> 5;

  const unsigned short* qbase = Qp + ((size_t)(b*32 + h)*64 + qt)*2048 + l*8;
  short8 qf0 = *reinterpret_cast<const short8*>(qbase);
  short8 qf1 = *reinterpret_cast<const short8*>(qbase + 512);
  short8 qf2 = *reinterpret_cast<const short8*>(qbase + 1024);
  short8 qf3 = *reinterpret_cast<const short8*>(qbase + 1536);

  const unsigned short* ksrc = Kp + (size_t)c*131072 + hh*512 + l*8;
  const unsigned short* vsrc = Vp + (size_t)c*131072 + hh*512 + l*8;

  f32x16 acc0, acc1;
  #pragma unroll
  for (int r = 0; r < 16; ++r) { acc0[r] = 0.f; acc1[r] = 0.f; }
  float l_loc = 0.f;

  auto stage = [&](int t, int buf) {
    __builtin_amdgcn_global_load_lds(
        (const __attribute__((address_space(1))) unsigned int*)(ksrc + (size_t)t*2048),
        (__attribute__((address_space(3))) unsigned int*)((char*)&kvlds[buf][0] + hh*1024),
        16, 0, 0);
    __builtin_amdgcn_global_load_lds(
        (const __attribute__((address_space(1))) unsigned int*)(vsrc + (size_t)t*2048),
        (__attribute__((address_space(3))) unsigned int*)((char*)&kvlds[buf][2048] + hh*1024),
        16, 0, 0);
  };

  auto body = [&](bool diag, int buf) {
    short8 ka = *reinterpret_cast<const short8*>(&kvlds[buf][l*8]);
    short8 kb = *reinterpret_cast<const short8*>(&kvlds[buf][512 + l*8]);
    short8 kc = *reinterpret_cast<const short8*>(&kvlds[buf][1024 + l*8]);
    short8 kd = *reinterpret_cast<const short8*>(&kvlds[buf][1536 + l*8]);

    f32x16 s;
    #pragma unroll
    for (int r = 0; r < 16; ++r) s[r] = 0.f;
    __builtin_amdgcn_s_setprio(1);
    s = __builtin_amdgcn_mfma_f32_32x32x16_bf16(ka, qf0, s, 0, 0, 0);
    s = __builtin_amdgcn_mfma_f32_32x32x16_bf16(kb, qf1, s, 0, 0, 0);
    s = __builtin_amdgcn_mfma_f32_32x32x16_bf16(kc, qf2, s, 0, 0, 0);
    s = __builtin_amdgcn_mfma_f32_32x32x16_bf16(kd, qf3, s, 0, 0, 0);
    __builtin_amdgcn_s_setprio(0);

    if (diag) {
      #pragma unroll
      for (int r = 0; r < 16; ++r) {
        const int ko = (r & 3) + 8*(r >> 2) + 4*hi;
        s[r] = (ko <= lq) ? s[r] : -3.0e38f;
      }
    }

    unsigned int w8[8];
    float ps = 0.f;
    #pragma unroll
    for (int i = 0; i < 8; ++i) {
      float p0 = exp2f(s[2*i]);
      float p1 = exp2f(s[2*i+1]);
      ps += p0 + p1;
      asm("v_cvt_pk_bf16_f32 %0, %1, %2" : "=v"(w8[i]) : "v"(p0), "v"(p1));
    }
    l_loc += ps;

    unsigned int x0 = w8[0], x1 = w8[1], y0 = w8[2], y1 = w8[3];
    asm("v_permlane32_swap_b32 %0, %1" : "+v"(x0), "+v"(y0));
    asm("v_permlane32_swap_b32 %0, %1" : "+v"(x1), "+v"(y1));
    unsigned int x2 = w8[4], x3 = w8[5], y2 = w8[6], y3 = w8[7];
    asm("v_permlane32_swap_b32 %0, %1" : "+v"(x2), "+v"(y2));
    asm("v_permlane32_swap_b32 %0, %1" : "+v"(x3), "+v"(y3));
    int4v p0i, p1i;
    p0i[0] = (int)x0; p0i[1] = (int)x1; p0i[2] = (int)y0; p0i[3] = (int)y1;
    p1i[0] = (int)x2; p1i[1] = (int)x3; p1i[2] = (int)y2; p1i[3] = (int)y3;
    short8 pa0 = __builtin_bit_cast(short8, p0i);
    short8 pa1 = __builtin_bit_cast(short8, p1i);

    short8 va = *reinterpret_cast<const short8*>(&kvlds[buf][2048 + l*8]);
    short8 vb = *reinterpret_cast<const short8*>(&kvlds[buf][2560 + l*8]);
    short8 vc = *reinterpret_cast<const short8*>(&kvlds[buf][3072 + l*8]);
    short8 vd = *reinterpret_cast<const short8*>(&kvlds[buf][3584 + l*8]);

    __builtin_amdgcn_s_setprio(1);
    acc0 = __builtin_amdgcn_mfma_f32_32x32x16_bf16(va, pa0, acc0, 0, 0, 0);
    acc0 = __builtin_amdgcn_mfma_f32_32x32x16_bf16(vb, pa1, acc0, 0, 0, 0);
    acc1 = __builtin_amdgcn_mfma_f32_32x32x16_bf16(vc, pa0, acc1, 0, 0, 0);
    acc1 = __builtin_amdgcn_mfma_f32_32x32x16_bf16(vd, pa1, acc1, 0, 0, 0);
    __builtin_amdgcn_s_setprio(0);
  };

  stage(0, 0);
  __syncthreads();
  for (int t = 0; ; ) {
    const int cur = t & 1;
    if (t < qt) stage(t + 1, cur ^ 1);
    body(t == qt, cur);
    if (++t > qt) break;
    __syncthreads();
  }

  const float l_run = l_loc + __shfl_xor(l_loc, 32);
  const float rl = 1.f / l_run;
  unsigned short* op = ctx + (size_t)(b*N_ + qt*32 + lq) * DOUT + h*HD_ + 4*hi;
  #pragma unroll
  for (int dt = 0; dt < 2; ++dt) {
    #pragma unroll
    for (int rq = 0; rq < 4; ++rq) {
      const float a0 = (dt ? acc1[4*rq+0] : acc0[4*rq+0]) * rl;
      const float a1 = (dt ? acc1[4*rq+1] : acc0[4*rq+1]) * rl;
      const float a2 = (dt ? acc1[4*rq+2] : acc0[4*rq+2]) * rl;
      const float a3 = (dt ? acc1[4*rq+3] : acc0[4*rq+3]) * rl;
      ushort4 st;
      st.x = f2bf(a0); st.y = f2bf(a1); st.z = f2bf(a2); st.w = f2bf(a3);
      *reinterpret_cast<ushort4*>(op + dt*32 + rq*8) = st;
    }
  }
}

// ---------------- launcher ----------------
extern "C" void kernel_launch(void* const* d_in, const int* in_sizes, int n_in,
                              void* d_out, int out_size, void* d_ws, size_t ws_size,
                              hipStream_t stream) {
  const float* x    = (const float*)d_in[0];
  const float* cosT = (const float*)d_in[1];
  const float* sinT = (const float*)d_in[2];
  const float* Wq   = (const float*)d_in[4];
  const float* Wk   = (const float*)d_in[5];
  const float* Wv   = (const float*)d_in[6];
  const float* Wo   = (const float*)d_in[7];
  float* out = (float*)d_out;

  char* ws = (char*)d_ws;
  unsigned short* xb     = (unsigned short*)(ws);              // 16.78 MB; reused as ctxb
  unsigned short* ctxb   = xb;
  unsigned short* Wqkv_t = (unsigned short*)(ws + 16777216);   // 12.58 MB (3072 x 2048)
  unsigned short* Wo_t   = (unsigned short*)(ws + 29360128);   //  8.39 MB
  unsigned short* Qp     = (unsigned short*)(ws + 37748736);   // 16.78 MB
  unsigned short* Kp     = (unsigned short*)(ws + 54525952);   //  4.19 MB
  unsigned short* Vp     = (unsigned short*)(ws + 58720256);   //  4.19 MB

  k_prep<<<dim3(288, 64), dim3(32, 8), 0, stream>>>(
      x, xb, Wq, Wk, Wv, Wo, Wqkv_t, Wo_t);

  k_gemm_qkv<<<dim3(3072/192, M_/256), 512, 0, stream>>>(
      xb, Wqkv_t, Qp, Kp, Vp, cosT, sinT);

  k_attn<<<dim3(1024), dim3(256), 0, stream>>>(Qp, Kp, Vp, ctxb);

  k_gemm_out<<<dim3(DOUT/128, M_/256), 512, 0, stream>>>(ctxb, Wo_t, out);
}